// Round 3
// baseline (1769.878 us; speedup 1.0000x reference)
//
#include <hip/hip_runtime.h>
#include <hip/hip_bf16.h>
#include <cmath>

typedef __hip_bfloat16 bf16;

static constexpr int N_P = 100000, N_D = 1000, N_S = 5000, NT = N_P + N_D + N_S;

__device__ __forceinline__ float tof(bf16 v) { return __bfloat162float(v); }
__device__ __forceinline__ float lda(bf16 v) { return __bfloat162float(v); }
__device__ __forceinline__ float lda(float v) { return v; }
__device__ __forceinline__ void sto(bf16* p, float v) { *p = __float2bfloat16(v); }
__device__ __forceinline__ void sto(float* p, float v) { *p = v; }

// monotone float<->uint encoding for atomicMax on floats
__device__ __forceinline__ unsigned fenc(float f) {
    unsigned u = __float_as_uint(f);
    return (u & 0x80000000u) ? ~u : (u | 0x80000000u);
}
__device__ __forceinline__ float fdec(unsigned u) {
    return (u & 0x80000000u) ? __uint_as_float(u & 0x7fffffffu) : __uint_as_float(~u);
}

// ---------------------------------------------------------------------------
// Runtime input-dtype detection: scan first 16384 half-words of x_p for bf16
// NaN/Inf bit patterns. Genuine bf16 N(0,1) data has none; fp32 data's low
// mantissa halves hit (h&0x7F80)==0x7F80 with P~1/256 -> ~64 hits expected.
// flag: 0 = inputs are bf16, 1 = inputs are fp32.
// ---------------------------------------------------------------------------
__global__ __launch_bounds__(256) void detect_kernel(const unsigned short* __restrict__ xp,
                                                     int* __restrict__ flag) {
    __shared__ int s;
    if (threadIdx.x == 0) s = 0;
    __syncthreads();
    int c = 0;
    for (int i = threadIdx.x; i < 16384; i += 256) {
        unsigned short h = xp[i];
        if ((h & 0x7F80) == 0x7F80) c = 1;
    }
    if (c) atomicOr(&s, 1);
    __syncthreads();
    if (threadIdx.x == 0) *flag = s;
}

// ---------------------------------------------------------------------------
// Canonicalize all 21 float tensors into one contiguous bf16 block.
// ---------------------------------------------------------------------------
struct ConvArgs {
    const void* src[21];
    long cum[22];
};

__global__ __launch_bounds__(256) void convert_kernel(ConvArgs a, bf16* __restrict__ dst,
                                                      long total, const int* __restrict__ flag) {
    const int f = *flag;
    for (long g = (long)blockIdx.x * 256 + threadIdx.x; g < total; g += (long)gridDim.x * 256) {
        int t = 0;
        while (g >= a.cum[t + 1]) t++;
        long i = g - a.cum[t];
        float v = f ? ((const float*)a.src[t])[i] : tof(((const bf16*)a.src[t])[i]);
        dst[g] = __float2bfloat16(v);
    }
}

// canonical-block element offsets (bf16 elements)
static constexpr size_t OFF_XP = 0;
static constexpr size_t OFF_XD = 6400000;
static constexpr size_t OFF_XS = 6528000;
static constexpr size_t OFF_WINP = 6848000;
static constexpr size_t OFF_BINP = 6852096;
static constexpr size_t OFF_WIND = 6852160;
static constexpr size_t OFF_BIND = 6860352;
static constexpr size_t OFF_WINS = 6860416;
static constexpr size_t OFF_BINS = 6864512;
static constexpr size_t OFF_WK = 6864576;
static constexpr size_t OFF_BK = 6889152;
static constexpr size_t OFF_WQ = 6889536;
static constexpr size_t OFF_BQ = 6914112;
static constexpr size_t OFF_WV = 6914496;
static constexpr size_t OFF_BV = 6939072;
static constexpr size_t OFF_WA = 6939456;
static constexpr size_t OFF_BA = 6964032;
static constexpr size_t OFF_AREL = 6964416;
static constexpr size_t OFF_MREL = 6972608;
static constexpr size_t OFF_PREL = 6980800;
static constexpr size_t OFF_SKIP = 6980832;
static constexpr size_t CW_TOTAL = 6980838;

// ---------------------------------------------------------------------------
// Small GEMM: Y[n,64] = X[n,FIN] @ W[FIN,64] + B[64]  (fp32 accum, OT store)
// ---------------------------------------------------------------------------
template <typename XT, typename WT, typename OT, int FIN>
__global__ __launch_bounds__(256) void gemm_kernel(const XT* __restrict__ X,
                                                   const WT* __restrict__ W,
                                                   const WT* __restrict__ Bb,
                                                   OT* __restrict__ Y, int n) {
    __shared__ float sW[FIN * 64];
    __shared__ float sX[16 * FIN];
    const int tid = threadIdx.x;
    for (int idx = tid; idx < FIN * 64; idx += 256) sW[idx] = lda(W[idx]);
    const int row0 = blockIdx.x * 16;
    for (int idx = tid; idx < 16 * FIN; idx += 256) {
        int r = idx / FIN, i = idx % FIN;
        int row = row0 + r;
        sX[idx] = (row < n) ? lda(X[(size_t)row * FIN + i]) : 0.f;
    }
    __syncthreads();
    const int j = tid & 63;
    const int rb = tid >> 6;
    const float bj = lda(Bb[j]);
    for (int k = 0; k < 4; k++) {
        int r = rb + 4 * k;
        int row = row0 + r;
        if (row >= n) continue;
        float acc = bj;
#pragma unroll 8
        for (int i = 0; i < FIN; i++) acc += sX[r * FIN + i] * sW[i * 64 + j];
        sto(&Y[(size_t)row * 64 + j], acc);
    }
}

// ---------------------------------------------------------------------------
// Fold a_rel / m_rel into effective per-(layer,relation) K/V weights (fp32).
// ---------------------------------------------------------------------------
__global__ __launch_bounds__(256) void eff_kernel(const bf16* __restrict__ Wk,
                                                  const bf16* __restrict__ bk,
                                                  const bf16* __restrict__ Wv,
                                                  const bf16* __restrict__ bv,
                                                  const bf16* __restrict__ a_rel,
                                                  const bf16* __restrict__ m_rel,
                                                  float* __restrict__ weff) {
    const int b = blockIdx.x;  // ((l*4+r)*2+kv)
    const int l = b >> 3, r = (b >> 1) & 3, kv = b & 1;
    const int st_of[4] = {0, 1, 1, 0};
    const int st = st_of[r];
    const bf16* W = (kv ? Wv : Wk) + (size_t)(l * 3 + st) * 4096;
    const bf16* B = (kv ? bv : bk) + (size_t)(l * 3 + st) * 64;
    const bf16* R = (kv ? m_rel : a_rel) + (size_t)(l * 4 + r) * 1024;
    float* out = weff + (size_t)b * 4160;
    for (int idx = threadIdx.x; idx < 4160; idx += 256) {
        if (idx < 4096) {
            int i = idx >> 6, j = idx & 63, h = j >> 4, e = j & 15;
            float acc = 0.f;
#pragma unroll
            for (int d = 0; d < 16; d++)
                acc += tof(W[i * 64 + h * 16 + d]) * tof(R[h * 256 + d * 16 + e]);
            out[idx] = acc;
        } else {
            int j = idx - 4096, h = j >> 4, e = j & 15;
            float acc = 0.f;
#pragma unroll
            for (int d = 0; d < 16; d++)
                acc += tof(B[h * 16 + d]) * tof(R[h * 256 + d * 16 + e]);
            out[idx] = acc;
        }
    }
}

// ---------------------------------------------------------------------------
// Edge phase. 64 threads per edge: t = h*16 + d.
// ---------------------------------------------------------------------------
__global__ __launch_bounds__(256) void alpha_kernel(const int* __restrict__ ei, int E,
                                                    const bf16* __restrict__ qdst,
                                                    const bf16* __restrict__ krel,
                                                    const bf16* __restrict__ prel,
                                                    float* __restrict__ alpha,
                                                    unsigned* __restrict__ mx) {
    long idx = (long)blockIdx.x * 256 + threadIdx.x;
    int e = (int)(idx >> 6);
    if (e >= E) return;
    int t = (int)(idx & 63), h = t >> 4;
    int src = ei[e], dst = ei[E + e];
    float p = tof(qdst[(size_t)dst * 64 + t]) * tof(krel[(size_t)src * 64 + t]);
    p += __shfl_xor(p, 8, 16);
    p += __shfl_xor(p, 4, 16);
    p += __shfl_xor(p, 2, 16);
    p += __shfl_xor(p, 1, 16);
    if ((t & 15) == 0) {
        float a = p * (tof(prel[h]) * 0.25f);  // * p_rel / sqrt(DH=16)
        alpha[(size_t)e * 4 + h] = a;
        atomicMax(&mx[(size_t)dst * 4 + h], fenc(a));
    }
}

__global__ __launch_bounds__(256) void exp_kernel(const int* __restrict__ ei, int E,
                                                  float* __restrict__ alpha,
                                                  const unsigned* __restrict__ mx,
                                                  float* __restrict__ den) {
    long idx = (long)blockIdx.x * 256 + threadIdx.x;
    if (idx >= (long)E * 4) return;
    int e = (int)(idx >> 2), h = (int)(idx & 3);
    int dst = ei[E + e];
    float a = expf(alpha[idx] - fdec(mx[(size_t)dst * 4 + h]));
    alpha[idx] = a;
    atomicAdd(&den[(size_t)dst * 4 + h], a);
}

__global__ __launch_bounds__(256) void scatter_kernel(const int* __restrict__ ei, int E,
                                                      const float* __restrict__ alpha,
                                                      const float* __restrict__ den,
                                                      const float* __restrict__ vrel,
                                                      float* __restrict__ outdst) {
    long idx = (long)blockIdx.x * 256 + threadIdx.x;
    int e = (int)(idx >> 6);
    if (e >= E) return;
    int t = (int)(idx & 63), h = t >> 4;
    int src = ei[e], dst = ei[E + e];
    float c = alpha[(size_t)e * 4 + h] / (den[(size_t)dst * 4 + h] + 1e-16f);
    atomicAdd(&outdst[(size_t)dst * 64 + t], vrel[(size_t)src * 64 + t] * c);
}

// ---------------------------------------------------------------------------
// Epilogue per type (IN-PLACE on X): x = s * (gelu(out) @ Wa + ba) + (1-s) * x
// ---------------------------------------------------------------------------
__global__ __launch_bounds__(256) void out_kernel(const float* __restrict__ Xout,
                                                  bf16* Xio,  // in-place, no restrict
                                                  const bf16* __restrict__ W,
                                                  const bf16* __restrict__ B,
                                                  const bf16* __restrict__ skip,
                                                  int n) {
    __shared__ float sW[4096];
    __shared__ float sX[1024];
    const int tid = threadIdx.x;
    for (int idx = tid; idx < 4096; idx += 256) sW[idx] = tof(W[idx]);
    const int row0 = blockIdx.x * 16;
    for (int idx = tid; idx < 1024; idx += 256) {
        int r = idx >> 6, i = idx & 63;
        int row = row0 + r;
        float v = (row < n) ? Xout[(size_t)row * 64 + i] : 0.f;
        sX[idx] = 0.5f * v * (1.0f + erff(v * 0.70710678118654752f));  // exact gelu
    }
    __syncthreads();
    const float s = 1.f / (1.f + expf(-tof(skip[0])));
    const int j = tid & 63, rb = tid >> 6;
    const float bj = tof(B[j]);
    for (int k = 0; k < 4; k++) {
        int r = rb + 4 * k;
        int row = row0 + r;
        if (row >= n) continue;
        float acc = bj;
#pragma unroll 8
        for (int i = 0; i < 64; i++) acc += sX[r * 64 + i] * sW[i * 64 + j];
        float xv = tof(Xio[(size_t)row * 64 + j]);
        sto(&Xio[(size_t)row * 64 + j], s * acc + (1.f - s) * xv);
    }
}

// ---------------------------------------------------------------------------
// Final store: dtype-matched to the detected input dtype.
// ---------------------------------------------------------------------------
__global__ __launch_bounds__(256) void final_kernel(const bf16* __restrict__ X, void* out,
                                                    long n, const int* __restrict__ flag) {
    const int f = *flag;
    long i = (long)blockIdx.x * 256 + threadIdx.x;
    if (i >= n) return;
    if (f)
        ((float*)out)[i] = tof(X[i]);
    else
        ((bf16*)out)[i] = X[i];
}

// ---------------------------------------------------------------------------
extern "C" void kernel_launch(void* const* d_in, const int* in_sizes, int n_in,
                              void* d_out, int out_size, void* d_ws, size_t ws_size,
                              hipStream_t stream) {
    const int* ei[4] = {(const int*)d_in[21], (const int*)d_in[22],
                        (const int*)d_in[23], (const int*)d_in[24]};

    // ---- Workspace layout (~115 MiB) ----
    char* w = (char*)d_ws;
    int* FLAG = (int*)w;          w += 64;
    bf16* CW = (bf16*)w;          w += ((CW_TOTAL * 2 + 63) / 64) * 64;  // canonical inputs
    bf16* X = (bf16*)w;           w += (size_t)NT * 64 * 2;
    bf16* Q = (bf16*)w;           w += (size_t)NT * 64 * 2;
    bf16* KREL = (bf16*)w;        w += (size_t)N_P * 64 * 2;
    float* VREL = (float*)w;      w += (size_t)N_P * 64 * 4;
    float* OUT = (float*)w;       w += (size_t)NT * 64 * 4;
    float* ALPHA = (float*)w;     w += (size_t)300000 * 4 * 4;
    unsigned* MX = (unsigned*)w;  w += (size_t)N_P * 4 * 4;
    float* DEN = (float*)w;       w += (size_t)N_P * 4 * 4;
    float* WEFF = (float*)w;      w += (size_t)16 * 4160 * 4;

    // dtype detect + canonicalize
    detect_kernel<<<1, 256, 0, stream>>>((const unsigned short*)d_in[0], FLAG);
    static const long sz[21] = {6400000, 128000, 320000, 4096, 64, 8192, 64, 4096, 64,
                                24576, 384, 24576, 384, 24576, 384, 24576, 384,
                                8192, 8192, 32, 6};
    ConvArgs ca;
    long cum = 0;
    for (int t = 0; t < 21; t++) {
        ca.src[t] = d_in[t];
        ca.cum[t] = cum;
        cum += sz[t];
    }
    ca.cum[21] = cum;
    convert_kernel<<<4096, 256, 0, stream>>>(ca, CW, cum, FLAG);

    const int Ns[3] = {N_P, N_D, N_S};
    const size_t toff[3] = {0, (size_t)N_P, (size_t)(N_P + N_D)};
    const int rst[4] = {0, 1, 1, 0};  // src type per relation
    const int rdt[4] = {1, 0, 2, 2};  // dst type per relation
    const int rE[4] = {300000, 300000, 100000, 100000};

    // input projections -> X
    gemm_kernel<bf16, bf16, bf16, 64><<<(N_P + 15) / 16, 256, 0, stream>>>(
        CW + OFF_XP, CW + OFF_WINP, CW + OFF_BINP, X, N_P);
    gemm_kernel<bf16, bf16, bf16, 128><<<(N_D + 15) / 16, 256, 0, stream>>>(
        CW + OFF_XD, CW + OFF_WIND, CW + OFF_BIND, X + toff[1] * 64, N_D);
    gemm_kernel<bf16, bf16, bf16, 64><<<(N_S + 15) / 16, 256, 0, stream>>>(
        CW + OFF_XS, CW + OFF_WINS, CW + OFF_BINS, X + toff[2] * 64, N_S);
    // effective relation K/V weights
    eff_kernel<<<16, 256, 0, stream>>>(CW + OFF_WK, CW + OFF_BK, CW + OFF_WV, CW + OFF_BV,
                                       CW + OFF_AREL, CW + OFF_MREL, WEFF);

    for (int l = 0; l < 2; l++) {
        for (int t = 0; t < 3; t++)
            gemm_kernel<bf16, bf16, bf16, 64><<<(Ns[t] + 15) / 16, 256, 0, stream>>>(
                X + toff[t] * 64, CW + OFF_WQ + (size_t)(l * 3 + t) * 4096,
                CW + OFF_BQ + (l * 3 + t) * 64, Q + toff[t] * 64, Ns[t]);
        hipMemsetAsync(OUT, 0, (size_t)NT * 64 * 4, stream);
        for (int r = 0; r < 4; r++) {
            const int st = rst[r], dt = rdt[r], E = rE[r];
            const float* wke = WEFF + (size_t)((l * 4 + r) * 2 + 0) * 4160;
            const float* wve = WEFF + (size_t)((l * 4 + r) * 2 + 1) * 4160;
            gemm_kernel<bf16, float, bf16, 64><<<(Ns[st] + 15) / 16, 256, 0, stream>>>(
                X + toff[st] * 64, wke, wke + 4096, KREL, Ns[st]);
            gemm_kernel<bf16, float, float, 64><<<(Ns[st] + 15) / 16, 256, 0, stream>>>(
                X + toff[st] * 64, wve, wve + 4096, VREL, Ns[st]);
            hipMemsetAsync(MX, 0, (size_t)Ns[dt] * 4 * sizeof(unsigned), stream);
            hipMemsetAsync(DEN, 0, (size_t)Ns[dt] * 4 * sizeof(float), stream);
            alpha_kernel<<<(int)(((long)E * 64 + 255) / 256), 256, 0, stream>>>(
                ei[r], E, Q + toff[dt] * 64, KREL, CW + OFF_PREL + (l * 4 + r) * 4, ALPHA, MX);
            exp_kernel<<<(int)(((long)E * 4 + 255) / 256), 256, 0, stream>>>(
                ei[r], E, ALPHA, MX, DEN);
            scatter_kernel<<<(int)(((long)E * 64 + 255) / 256), 256, 0, stream>>>(
                ei[r], E, ALPHA, DEN, VREL, OUT + toff[dt] * 64);
        }
        for (int t = 0; t < 3; t++)
            out_kernel<<<(Ns[t] + 15) / 16, 256, 0, stream>>>(
                OUT + toff[t] * 64, X + toff[t] * 64, CW + OFF_WA + (size_t)(l * 3 + t) * 4096,
                CW + OFF_BA + (l * 3 + t) * 64, CW + OFF_SKIP + (l * 3 + t), Ns[t]);
    }
    final_kernel<<<(int)(((long)NT * 64 + 255) / 256), 256, 0, stream>>>(
        X, d_out, (long)NT * 64, FLAG);
}

// Round 4
// 1014.080 us; speedup vs baseline: 1.7453x; 1.7453x over previous
//
#include <hip/hip_runtime.h>
#include <cmath>

typedef unsigned short ush;  // bf16 raw bits
typedef __attribute__((ext_vector_type(8))) short short8;
typedef __attribute__((ext_vector_type(4))) float floatx4;

static constexpr int N_P = 100000, N_D = 1000, N_S = 5000, NT = N_P + N_D + N_S;

__device__ __forceinline__ float b2f(ush b) {
    return __uint_as_float(((unsigned)b) << 16);
}
__device__ __forceinline__ ush f2b(float f) {
    unsigned u = __float_as_uint(f);
    return (ush)((u + 0x7FFFu + ((u >> 16) & 1u)) >> 16);
}

// monotone float<->uint encoding for atomicMax on floats
__device__ __forceinline__ unsigned fenc(float f) {
    unsigned u = __float_as_uint(f);
    return (u & 0x80000000u) ? ~u : (u | 0x80000000u);
}
__device__ __forceinline__ float fdec(unsigned u) {
    return (u & 0x80000000u) ? __uint_as_float(u & 0x7fffffffu) : __uint_as_float(~u);
}

// ---------------------------------------------------------------------------
// Input dtype detection (fp32 vs bf16) — scan for bf16 NaN/Inf bit patterns.
// ---------------------------------------------------------------------------
__global__ __launch_bounds__(256) void detect_kernel(const ush* __restrict__ xp,
                                                     int* __restrict__ flag) {
    __shared__ int s;
    if (threadIdx.x == 0) s = 0;
    __syncthreads();
    int c = 0;
    for (int i = threadIdx.x; i < 16384; i += 256) {
        ush h = xp[i];
        if ((h & 0x7F80) == 0x7F80) c = 1;
    }
    if (c) atomicOr(&s, 1);
    __syncthreads();
    if (threadIdx.x == 0) *flag = s;
}

struct ConvArgs {
    const void* src[21];
    long cum[22];
};

__global__ __launch_bounds__(256) void convert_kernel(ConvArgs a, ush* __restrict__ dst,
                                                      long total, const int* __restrict__ flag) {
    const int f = *flag;
    for (long g = (long)blockIdx.x * 256 + threadIdx.x; g < total; g += (long)gridDim.x * 256) {
        int t = 0;
        while (g >= a.cum[t + 1]) t++;
        long i = g - a.cum[t];
        float v = f ? ((const float*)a.src[t])[i] : b2f(((const ush*)a.src[t])[i]);
        dst[g] = f2b(v);
    }
}

// canonical-block element offsets (bf16 elements)
static constexpr size_t OFF_XP = 0;
static constexpr size_t OFF_XD = 6400000;
static constexpr size_t OFF_XS = 6528000;
static constexpr size_t OFF_WINP = 6848000;
static constexpr size_t OFF_BINP = 6852096;
static constexpr size_t OFF_WIND = 6852160;
static constexpr size_t OFF_BIND = 6860352;
static constexpr size_t OFF_WINS = 6860416;
static constexpr size_t OFF_BINS = 6864512;
static constexpr size_t OFF_WK = 6864576;
static constexpr size_t OFF_BK = 6889152;
static constexpr size_t OFF_WQ = 6889536;
static constexpr size_t OFF_BQ = 6914112;
static constexpr size_t OFF_WV = 6914496;
static constexpr size_t OFF_BV = 6939072;
static constexpr size_t OFF_WA = 6939456;
static constexpr size_t OFF_BA = 6964032;
static constexpr size_t OFF_AREL = 6964416;
static constexpr size_t OFF_MREL = 6972608;
static constexpr size_t OFF_PREL = 6980800;
static constexpr size_t OFF_SKIP = 6980832;
static constexpr size_t CW_TOTAL = 6980838;

// ---------------------------------------------------------------------------
// Fold a_rel/m_rel into effective K|V weights, bf16, fused per (l,r):
// out block: Wcat[64][128] (cols 0-63 = K-eff, 64-127 = V-eff) + bias[128].
// ---------------------------------------------------------------------------
__global__ __launch_bounds__(256) void eff_kernel(const ush* __restrict__ CW,
                                                  ush* __restrict__ weff) {
    const int b = blockIdx.x;  // l*4+r
    const int l = b >> 2, r = b & 3;
    const int st_of[4] = {0, 1, 1, 0};
    const int st = st_of[r];
    ush* out = weff + (size_t)b * 8320;
    for (int idx = threadIdx.x; idx < 8320; idx += 256) {
        int n, k;
        if (idx < 8192) { k = idx >> 7; n = idx & 127; }
        else { k = -1; n = idx - 8192; }
        int kv = n >= 64;
        int j = n & 63, h = j >> 4, e = j & 15;
        const ush* W = CW + (kv ? OFF_WV : OFF_WK) + (size_t)(l * 3 + st) * 4096;
        const ush* B = CW + (kv ? OFF_BV : OFF_BK) + (size_t)(l * 3 + st) * 64;
        const ush* R = CW + (kv ? OFF_MREL : OFF_AREL) + (size_t)(l * 4 + r) * 1024;
        float acc = 0.f;
        if (k >= 0) {
#pragma unroll
            for (int d = 0; d < 16; d++)
                acc += b2f(W[k * 64 + h * 16 + d]) * b2f(R[h * 256 + d * 16 + e]);
        } else {
#pragma unroll
            for (int d = 0; d < 16; d++)
                acc += b2f(B[h * 16 + d]) * b2f(R[h * 256 + d * 16 + e]);
        }
        out[idx] = f2b(acc);
    }
}

// ---------------------------------------------------------------------------
// MFMA GEMM: Y[M x NOUT] = X[M x K](bf16) @ W[K x NOUT](bf16) + bias.
// Block = 256 thr (4 waves) x 64 rows. mfma_f32_16x16x32_bf16 layouts:
//   A: lane l holds A[m=l&15][k=(l>>4)*8+j]   (j=0..7)
//   B: lane l holds B[k=(l>>4)*8+j][n=l&15]
//   D: lane l reg r -> row=(l>>4)*4+r, col=l&15
// KV=true: cols 0-63 -> Yb (bf16), cols 64-127 -> Yf (fp32).
// ---------------------------------------------------------------------------
template <int K, int NOUT, bool KV>
__global__ __launch_bounds__(256) void mfma_proj(const ush* __restrict__ X,
                                                 const ush* __restrict__ W,
                                                 const ush* __restrict__ bias,
                                                 ush* __restrict__ Yb,
                                                 float* __restrict__ Yf, int M) {
    constexpr int NF = (K / 32) * (NOUT / 16);
    __shared__ short sA[64][K + 8];
    __shared__ short sB[NF][512];
    const int tid = threadIdx.x;
    const int row0 = blockIdx.x * 64;
    // stage X tile (vectorized 16B)
    for (int cid = tid; cid < 64 * K / 8; cid += 256) {
        int r = cid / (K / 8), c0 = (cid % (K / 8)) * 8;
        int row = row0 + r;
        short8 v = {0, 0, 0, 0, 0, 0, 0, 0};
        if (row < M) v = *(const short8*)(const void*)(X + (size_t)row * K + c0);
        *(short8*)(&sA[r][c0]) = v;
    }
    // stage W in B-fragment order
    for (int u = tid; u < NF * 64; u += 256) {
        int f = u >> 6, l = u & 63;
        int s = f / (NOUT / 16), c = f % (NOUT / 16);
        int kbase = 32 * s + ((l >> 4) << 3), n = 16 * c + (l & 15);
        short8 v;
#pragma unroll
        for (int j = 0; j < 8; j++) v[j] = (short)W[(size_t)(kbase + j) * NOUT + n];
        *(short8*)(&sB[f][l * 8]) = v;
    }
    __syncthreads();
    const int w = tid >> 6, l = tid & 63;
    floatx4 acc[NOUT / 16];
#pragma unroll
    for (int c = 0; c < NOUT / 16; c++) {
        float bv = b2f(bias[16 * c + (l & 15)]);
        acc[c] = (floatx4){bv, bv, bv, bv};
    }
#pragma unroll
    for (int s = 0; s < K / 32; s++) {
        short8 a = *(const short8*)(&sA[16 * w + (l & 15)][32 * s + ((l >> 4) << 3)]);
#pragma unroll
        for (int c = 0; c < NOUT / 16; c++) {
            short8 b = *(const short8*)(&sB[s * (NOUT / 16) + c][l * 8]);
            acc[c] = __builtin_amdgcn_mfma_f32_16x16x32_bf16(a, b, acc[c], 0, 0, 0);
        }
    }
#pragma unroll
    for (int c = 0; c < NOUT / 16; c++)
#pragma unroll
        for (int r = 0; r < 4; r++) {
            int row = row0 + 16 * w + ((l >> 4) << 2) + r;
            if (row >= M) continue;
            if (!KV || c < 4) {
                Yb[(size_t)row * 64 + 16 * c + (l & 15)] = f2b(acc[c][r]);
            } else {
                Yf[(size_t)row * 64 + 16 * (c - 4) + (l & 15)] = acc[c][r];
            }
        }
}

// ---------------------------------------------------------------------------
// MFMA epilogue: X = s*(gelu(num/(den+eps)) @ Wa + ba) + (1-s)*X  (in place)
// DUAL: two (num,den) pairs summed (disease dst of two relations).
// ---------------------------------------------------------------------------
template <bool DUAL>
__global__ __launch_bounds__(256) void mfma_epi(const float* __restrict__ NA,
                                                const float* __restrict__ NB,
                                                const float* __restrict__ DA,
                                                const float* __restrict__ DB,
                                                ush* Xio, const ush* __restrict__ W,
                                                const ush* __restrict__ bias,
                                                const ush* __restrict__ skip, int M) {
    __shared__ short sA[64][72];
    __shared__ short sB[8][512];
    const int tid = threadIdx.x;
    const int row0 = blockIdx.x * 64;
    for (int cid = tid; cid < 512; cid += 256) {
        int r = cid >> 3, c0 = (cid & 7) * 8;
        int row = row0 + r, h = c0 >> 4;
        float vals[8];
        if (row < M) {
            float da = DA[(size_t)row * 4 + h] + 1e-16f;
            float db = DUAL ? DB[(size_t)row * 4 + h] + 1e-16f : 1.f;
#pragma unroll
            for (int j = 0; j < 8; j++) {
                float v = NA[(size_t)row * 64 + c0 + j] / da;
                if (DUAL) v += NB[(size_t)row * 64 + c0 + j] / db;
                vals[j] = 0.5f * v * (1.0f + erff(v * 0.70710678118654752f));
            }
        } else {
#pragma unroll
            for (int j = 0; j < 8; j++) vals[j] = 0.f;
        }
        short8 sv;
#pragma unroll
        for (int j = 0; j < 8; j++) sv[j] = (short)f2b(vals[j]);
        *(short8*)(&sA[r][c0]) = sv;
    }
    for (int u = tid; u < 512; u += 256) {
        int f = u >> 6, l = u & 63;
        int s = f >> 2, c = f & 3;
        int kbase = 32 * s + ((l >> 4) << 3), n = 16 * c + (l & 15);
        short8 v;
#pragma unroll
        for (int j = 0; j < 8; j++) v[j] = (short)W[(size_t)(kbase + j) * 64 + n];
        *(short8*)(&sB[f][l * 8]) = v;
    }
    __syncthreads();
    const int w = tid >> 6, l = tid & 63;
    const float sg = 1.f / (1.f + expf(-b2f(skip[0])));
    floatx4 acc[4];
#pragma unroll
    for (int c = 0; c < 4; c++) {
        float bv = b2f(bias[16 * c + (l & 15)]);
        acc[c] = (floatx4){bv, bv, bv, bv};
    }
#pragma unroll
    for (int s = 0; s < 2; s++) {
        short8 a = *(const short8*)(&sA[16 * w + (l & 15)][32 * s + ((l >> 4) << 3)]);
#pragma unroll
        for (int c = 0; c < 4; c++) {
            short8 b = *(const short8*)(&sB[s * 4 + c][l * 8]);
            acc[c] = __builtin_amdgcn_mfma_f32_16x16x32_bf16(a, b, acc[c], 0, 0, 0);
        }
    }
#pragma unroll
    for (int c = 0; c < 4; c++)
#pragma unroll
        for (int r = 0; r < 4; r++) {
            int row = row0 + 16 * w + ((l >> 4) << 2) + r;
            if (row >= M) continue;
            size_t off = (size_t)row * 64 + 16 * c + (l & 15);
            float xv = b2f(Xio[off]);
            Xio[off] = f2b(sg * acc[c][r] + (1.f - sg) * xv);
        }
}

// ---------------------------------------------------------------------------
// Edge phase: alpha (4 thr/edge, one per head), then fused exp+scatter.
// ---------------------------------------------------------------------------
__global__ __launch_bounds__(256) void alpha4_kernel(const int* __restrict__ ei, int E,
                                                     const ush* __restrict__ qdst,
                                                     const ush* __restrict__ krel,
                                                     const ush* __restrict__ prel,
                                                     float* __restrict__ alpha,
                                                     unsigned* __restrict__ mx) {
    long idx = (long)blockIdx.x * 256 + threadIdx.x;
    int e = (int)(idx >> 2);
    if (e >= E) return;
    int h = (int)(idx & 3);
    int src = ei[e], dst = ei[E + e];
    const short8 q0 = *(const short8*)(const void*)(qdst + (size_t)dst * 64 + h * 16);
    const short8 q1 = *(const short8*)(const void*)(qdst + (size_t)dst * 64 + h * 16 + 8);
    const short8 k0 = *(const short8*)(const void*)(krel + (size_t)src * 64 + h * 16);
    const short8 k1 = *(const short8*)(const void*)(krel + (size_t)src * 64 + h * 16 + 8);
    float p = 0.f;
#pragma unroll
    for (int j = 0; j < 8; j++) p += b2f((ush)q0[j]) * b2f((ush)k0[j]);
#pragma unroll
    for (int j = 0; j < 8; j++) p += b2f((ush)q1[j]) * b2f((ush)k1[j]);
    float a = p * (b2f(prel[h]) * 0.25f);  // * p_rel / sqrt(DH=16)
    alpha[(size_t)e * 4 + h] = a;
    atomicMax(&mx[(size_t)dst * 4 + h], fenc(a));
}

__global__ __launch_bounds__(256) void scatter_kernel(const int* __restrict__ ei, int E,
                                                      const float* __restrict__ alpha,
                                                      const unsigned* __restrict__ mx,
                                                      float* __restrict__ den,
                                                      const float* __restrict__ vrel,
                                                      float* __restrict__ num) {
    long idx = (long)blockIdx.x * 256 + threadIdx.x;
    int e = (int)(idx >> 6);
    if (e >= E) return;
    int t = (int)(idx & 63), h = t >> 4;
    int src = ei[e], dst = ei[E + e];
    float a = expf(alpha[(size_t)e * 4 + h] - fdec(mx[(size_t)dst * 4 + h]));
    if ((t & 15) == 0) atomicAdd(&den[(size_t)dst * 4 + h], a);
    atomicAdd(&num[(size_t)dst * 64 + t], vrel[(size_t)src * 64 + t] * a);
}

// ---------------------------------------------------------------------------
__global__ __launch_bounds__(256) void final_kernel(const ush* __restrict__ X, void* out,
                                                    long n, const int* __restrict__ flag) {
    const int f = *flag;
    long i = (long)blockIdx.x * 256 + threadIdx.x;
    if (i >= n) return;
    if (f)
        ((float*)out)[i] = b2f(X[i]);
    else
        ((ush*)out)[i] = X[i];
}

// ---------------------------------------------------------------------------
extern "C" void kernel_launch(void* const* d_in, const int* in_sizes, int n_in,
                              void* d_out, int out_size, void* d_ws, size_t ws_size,
                              hipStream_t stream) {
    const int* ei[4] = {(const int*)d_in[21], (const int*)d_in[22],
                        (const int*)d_in[23], (const int*)d_in[24]};

    // ---- Workspace layout (~117 MiB) ----
    char* w = (char*)d_ws;
    int* FLAG = (int*)w;       w += 64;
    ush* CW = (ush*)w;         w += ((CW_TOTAL * 2 + 63) / 64) * 64;
    ush* WEFFB = (ush*)w;      w += ((size_t)8 * 8320 * 2 + 63) / 64 * 64;
    ush* X = (ush*)w;          w += (size_t)NT * 64 * 2;
    ush* Q = (ush*)w;          w += (size_t)NT * 64 * 2;
    ush* KREL = (ush*)w;       w += (size_t)N_P * 64 * 2;
    float* VREL = (float*)w;   w += (size_t)N_P * 64 * 4;
    float* OUT = (float*)w;    w += (size_t)NT * 64 * 4;   // num: t0<-r1, t1<-r0, t2<-r2
    float* OUTB = (float*)w;   w += (size_t)N_S * 64 * 4;  // num: t2<-r3
    float* ALPHA = (float*)w;  w += (size_t)300000 * 4 * 4;
    unsigned* MX = (unsigned*)w;  w += (size_t)111000 * 4 * 4;  // per-relation regions
    float* DEN = (float*)w;    w += (size_t)111000 * 4 * 4;

    // per-relation mx/den offsets (elements of 4-wide): r0(dst=D):0, r1(dst=P):1000,
    // r2(dst=S):101000, r3(dst=S):106000
    const size_t droff[4] = {0, 1000, 101000, 106000};

    detect_kernel<<<1, 256, 0, stream>>>((const ush*)d_in[0], FLAG);
    static const long sz[21] = {6400000, 128000, 320000, 4096, 64, 8192, 64, 4096, 64,
                                24576, 384, 24576, 384, 24576, 384, 24576, 384,
                                8192, 8192, 32, 6};
    ConvArgs ca;
    long cum = 0;
    for (int t = 0; t < 21; t++) {
        ca.src[t] = d_in[t];
        ca.cum[t] = cum;
        cum += sz[t];
    }
    ca.cum[21] = cum;
    convert_kernel<<<4096, 256, 0, stream>>>(ca, CW, cum, FLAG);

    const int Ns[3] = {N_P, N_D, N_S};
    const size_t toff[3] = {0, (size_t)N_P, (size_t)(N_P + N_D)};
    const int rst[4] = {0, 1, 1, 0};
    const int rdt[4] = {1, 0, 2, 2};
    const int rE[4] = {300000, 300000, 100000, 100000};

    eff_kernel<<<8, 256, 0, stream>>>(CW, WEFFB);

    // input projections -> X
    mfma_proj<64, 64, false><<<(N_P + 63) / 64, 256, 0, stream>>>(
        CW + OFF_XP, CW + OFF_WINP, CW + OFF_BINP, X, nullptr, N_P);
    mfma_proj<128, 64, false><<<(N_D + 63) / 64, 256, 0, stream>>>(
        CW + OFF_XD, CW + OFF_WIND, CW + OFF_BIND, X + toff[1] * 64, nullptr, N_D);
    mfma_proj<64, 64, false><<<(N_S + 63) / 64, 256, 0, stream>>>(
        CW + OFF_XS, CW + OFF_WINS, CW + OFF_BINS, X + toff[2] * 64, nullptr, N_S);

    for (int l = 0; l < 2; l++) {
        for (int t = 0; t < 3; t++)
            mfma_proj<64, 64, false><<<(Ns[t] + 63) / 64, 256, 0, stream>>>(
                X + toff[t] * 64, CW + OFF_WQ + (size_t)(l * 3 + t) * 4096,
                CW + OFF_BQ + (l * 3 + t) * 64, Q + toff[t] * 64, nullptr, Ns[t]);
        hipMemsetAsync(OUT, 0, (size_t)NT * 64 * 4, stream);
        hipMemsetAsync(OUTB, 0, (size_t)N_S * 64 * 4, stream);
        hipMemsetAsync(MX, 0, (size_t)111000 * 4 * 4, stream);
        hipMemsetAsync(DEN, 0, (size_t)111000 * 4 * 4, stream);
        for (int r = 0; r < 4; r++) {
            const int st = rst[r], dt = rdt[r], E = rE[r];
            const ush* we = WEFFB + (size_t)(l * 4 + r) * 8320;
            mfma_proj<64, 128, true><<<(Ns[st] + 63) / 64, 256, 0, stream>>>(
                X + toff[st] * 64, we, we + 8192, KREL, VREL, Ns[st]);
            unsigned* mx = MX + droff[r] * 4;
            float* den = DEN + droff[r] * 4;
            float* num = (r == 3) ? OUTB : OUT + toff[dt] * 64;
            alpha4_kernel<<<(int)(((long)E * 4 + 255) / 256), 256, 0, stream>>>(
                ei[r], E, Q + toff[dt] * 64, KREL, CW + OFF_PREL + (l * 4 + r) * 4, ALPHA, mx);
            scatter_kernel<<<(int)(((long)E * 64 + 255) / 256), 256, 0, stream>>>(
                ei[r], E, ALPHA, mx, den, VREL, num);
        }
        // epilogues: t0 den<-r1, t1 den<-r0, t2 dual (r2, r3)
        mfma_epi<false><<<(N_P + 63) / 64, 256, 0, stream>>>(
            OUT + toff[0] * 64, nullptr, DEN + droff[1] * 4, nullptr, X + toff[0] * 64,
            CW + OFF_WA + (size_t)(l * 3 + 0) * 4096, CW + OFF_BA + (l * 3 + 0) * 64,
            CW + OFF_SKIP + (l * 3 + 0), N_P);
        mfma_epi<false><<<(N_D + 63) / 64, 256, 0, stream>>>(
            OUT + toff[1] * 64, nullptr, DEN + droff[0] * 4, nullptr, X + toff[1] * 64,
            CW + OFF_WA + (size_t)(l * 3 + 1) * 4096, CW + OFF_BA + (l * 3 + 1) * 64,
            CW + OFF_SKIP + (l * 3 + 1), N_D);
        mfma_epi<true><<<(N_S + 63) / 64, 256, 0, stream>>>(
            OUT + toff[2] * 64, OUTB, DEN + droff[2] * 4, DEN + droff[3] * 4, X + toff[2] * 64,
            CW + OFF_WA + (size_t)(l * 3 + 2) * 4096, CW + OFF_BA + (l * 3 + 2) * 64,
            CW + OFF_SKIP + (l * 3 + 2), N_S);
    }
    final_kernel<<<(int)(((long)NT * 64 + 255) / 256), 256, 0, stream>>>(
        X, d_out, (long)NT * 64, FLAG);
}